// Round 3
// baseline (485.371 us; speedup 1.0000x reference)
//
#include <hip/hip_runtime.h>

// Problem constants
#define B_TOK 32768
#define D_IN  256
#define H1D   512
#define H2D   256
#define NE    16
#define NO    64

typedef _Float16 half8 __attribute__((ext_vector_type(8)));
typedef _Float16 half4 __attribute__((ext_vector_type(4)));
typedef float   float4_t __attribute__((ext_vector_type(4)));

// ---------------------------------------------------------------------------
// Pack W1 [E][D][H1] fp32 -> fragment-linear fp16.
// Fragment (e, mtile 0..31, kt 0..7): lane holds W1[e][kt*32+q*8+j][mt*16+l16]
// ---------------------------------------------------------------------------
__global__ void pack_w1(const float* __restrict__ W1, _Float16* __restrict__ w1p) {
  int t = blockIdx.x * 256 + threadIdx.x;        // 262144 threads
  int lane = t & 63;
  int kt   = (t >> 6) & 7;
  int ntg  = (t >> 9) & 31;
  int e    = t >> 14;
  int n  = ntg * 16 + (lane & 15);
  int kb = kt * 32 + (lane >> 4) * 8;
  half8 v;
  #pragma unroll
  for (int j = 0; j < 8; ++j)
    v[j] = (_Float16)W1[((size_t)(e * D_IN + kb + j)) * H1D + n];
  *(half8*)(w1p + (size_t)t * 8) = v;
}

// Pack W2 [E][H1][H2] fp32 -> fragments (e, ntile 0..15, ktile 0..15)
__global__ void pack_w2(const float* __restrict__ W2, _Float16* __restrict__ w2p) {
  int t = blockIdx.x * 256 + threadIdx.x;        // 262144 threads
  int lane = t & 63;
  int ktg  = (t >> 6) & 15;
  int ntg  = (t >> 10) & 15;
  int e    = t >> 14;
  int n  = ntg * 16 + (lane & 15);
  int kb = ktg * 32 + (lane >> 4) * 8;
  half8 v;
  #pragma unroll
  for (int j = 0; j < 8; ++j)
    v[j] = (_Float16)W2[((size_t)(e * H1D + kb + j)) * H2D + n];
  *(half8*)(w2p + (size_t)t * 8) = v;
}

// Pack gate_w [D][E] -> 8 B-fragments (kt 0..7)
__global__ void pack_gate(const float* __restrict__ gw, _Float16* __restrict__ gwp) {
  int t = threadIdx.x;                            // 512 threads, 1 block
  int lane = t & 63;
  int kt   = t >> 6;
  int e  = lane & 15;
  int kb = kt * 32 + (lane >> 4) * 8;
  half8 v;
  #pragma unroll
  for (int j = 0; j < 8; ++j)
    v[j] = (_Float16)gw[(kb + j) * NE + e];
  *(half8*)(gwp + (size_t)t * 8) = v;
}

// w3h[e][h2] = W3[e][h2][:] . head_w ;  c3[e] = b3[e][:] . head_w
__global__ void w3h_kernel(const float* __restrict__ W3, const float* __restrict__ b3,
                           const float* __restrict__ hw, float* __restrict__ w3h,
                           float* __restrict__ c3) {
  int t = blockIdx.x * 256 + threadIdx.x;
  if (t < NE * H2D) {
    int e = t >> 8, h = t & 255;
    float s = 0.f;
    #pragma unroll
    for (int o = 0; o < NO; ++o) s = fmaf(W3[((size_t)(e * H2D + h)) * NO + o], hw[o], s);
    w3h[t] = s;
  } else if (t < NE * H2D + NE) {
    int e = t - NE * H2D;
    float s = 0.f;
    #pragma unroll
    for (int o = 0; o < NO; ++o) s = fmaf(b3[e * NO + o], hw[o], s);
    c3[e] = s;
  }
}

// ---------------------------------------------------------------------------
// Fused main kernel. 512 blocks x 512 threads (8 waves), 64 tokens/block.
// x tile in registers (128 VGPR) for the whole kernel.
// Double-buffered full-width h1 in LDS -> exactly ONE barrier per expert:
//   L1(e) [w1 global + x regs] -> h1[e&1] -> barrier -> L2(e) [h1 LDS + w2
//   global] -> epilogue (regs) -> L1(e+1) into h1[(e+1)&1]  (no barrier).
// Weight loads software-pipelined 1 k-tile ahead.
// ---------------------------------------------------------------------------
#define H1STR 520   // halves: 512 + 8 pad

__global__ __launch_bounds__(512, 2) void moe_main(
    const float* __restrict__ x,
    const float* __restrict__ b1,
    const float* __restrict__ b2,
    const _Float16* __restrict__ w1p,
    const _Float16* __restrict__ w2p,
    const _Float16* __restrict__ gwp,
    const float* __restrict__ gb,
    const float* __restrict__ w3h,
    const float* __restrict__ c3,
    const float* __restrict__ head_b,
    float* __restrict__ out) {
  __shared__ _Float16 h1_lds[2][64 * H1STR];       // 133 KB
  __shared__ float g_lds[NE * 68];                 // [e][token] padded
  __shared__ float fin[8 * 64];

  const int tid  = threadIdx.x;
  const int w    = tid >> 6;                       // 0..7
  const int lane = tid & 63;
  const int q    = lane >> 4;
  const int l16  = lane & 15;
  const int m0   = blockIdx.x * 64;
  const int tok_lane = (l16 >> 2) * 16 + q * 4 + (l16 & 3);

  // ---- one-time: x tile into register fragments xf[token-tile][kt] --------
  half8 xf[4][8];
  #pragma unroll
  for (int nt = 0; nt < 4; ++nt) {
    const float* xr = x + (size_t)(m0 + nt * 16 + l16) * D_IN + q * 8;
    #pragma unroll
    for (int kt = 0; kt < 8; ++kt) {
      float4_t v0 = *(const float4_t*)(xr + kt * 32);
      float4_t v1 = *(const float4_t*)(xr + kt * 32 + 4);
      half8 h;
      h[0] = (_Float16)v0[0]; h[1] = (_Float16)v0[1];
      h[2] = (_Float16)v0[2]; h[3] = (_Float16)v0[3];
      h[4] = (_Float16)v1[0]; h[5] = (_Float16)v1[1];
      h[6] = (_Float16)v1[2]; h[7] = (_Float16)v1[3];
      xf[nt][kt] = h;
    }
  }

  // ---- one-time: gates via MFMA + shuffle softmax (waves 0..3, tile = w) --
  if (w < 4) {
    float gbv = gb[l16];
    #pragma unroll
    for (int mt = 0; mt < 4; ++mt) {
      if (mt == w) {   // wave-uniform; keeps mt compile-time constant
        float4_t lg = (float4_t){0.f, 0.f, 0.f, 0.f};
        #pragma unroll
        for (int kt = 0; kt < 8; ++kt) {
          half8 bfr = *(const half8*)(gwp + (size_t)kt * 512 + lane * 8);
          lg = __builtin_amdgcn_mfma_f32_16x16x32_f16(xf[mt][kt], bfr, lg, 0, 0, 0);
        }
        #pragma unroll
        for (int r = 0; r < 4; ++r) {
          float v = lg[r] + gbv;                   // logit[token][e=l16]
          float m = v;
          m = fmaxf(m, __shfl_xor(m, 1));
          m = fmaxf(m, __shfl_xor(m, 2));
          m = fmaxf(m, __shfl_xor(m, 4));
          m = fmaxf(m, __shfl_xor(m, 8));
          float p = __expf(v - m);
          float s = p;
          s += __shfl_xor(s, 1);
          s += __shfl_xor(s, 2);
          s += __shfl_xor(s, 4);
          s += __shfl_xor(s, 8);
          g_lds[l16 * 68 + mt * 16 + q * 4 + r] = p / s;
        }
      }
    }
  }

  float yacc = 0.f;

  // per-wave weight bases (wave w: h1col tiles w*4.., h2col tiles w*2..)
  const _Float16* w1base = w1p + ((size_t)(w * 4 * 8)) * 512 + lane * 8;
  const _Float16* w2base = w2p + ((size_t)(w * 2 * 16)) * 512 + lane * 8;

  for (int e = 0; e < NE; ++e) {
    _Float16* h1b = h1_lds[e & 1];
    const _Float16* w1e = w1base + (size_t)e * (32 * 8 * 512);
    const _Float16* w2e = w2base + (size_t)e * (16 * 16 * 512);

    // ================= L1: h1^T = W1^T x, software-pipelined ===============
    float4_t a1[4][4];
    #pragma unroll
    for (int mt = 0; mt < 4; ++mt)
      #pragma unroll
      for (int nt = 0; nt < 4; ++nt)
        a1[mt][nt] = (float4_t){0.f, 0.f, 0.f, 0.f};

    half8 wc[4], wn[4];
    #pragma unroll
    for (int mt = 0; mt < 4; ++mt)
      wc[mt] = *(const half8*)(w1e + (size_t)(mt * 8 + 0) * 512);
    #pragma unroll
    for (int kt = 0; kt < 8; ++kt) {
      if (kt < 7) {
        #pragma unroll
        for (int mt = 0; mt < 4; ++mt)
          wn[mt] = *(const half8*)(w1e + (size_t)(mt * 8 + kt + 1) * 512);
      }
      #pragma unroll
      for (int mt = 0; mt < 4; ++mt)
        #pragma unroll
        for (int nt = 0; nt < 4; ++nt)
          a1[mt][nt] = __builtin_amdgcn_mfma_f32_16x16x32_f16(
              wc[mt], xf[nt][kt], a1[mt][nt], 0, 0, 0);
      #pragma unroll
      for (int mt = 0; mt < 4; ++mt) wc[mt] = wn[mt];
    }

    // bias + relu + b64 stores (lane: 4 consecutive h1cols of one token)
    #pragma unroll
    for (int mt = 0; mt < 4; ++mt) {
      int colbase = (w * 4 + mt) * 16 + q * 4;
      float4_t bb = *(const float4_t*)(b1 + e * H1D + colbase);
      #pragma unroll
      for (int nt = 0; nt < 4; ++nt) {
        half4 hv;
        #pragma unroll
        for (int r = 0; r < 4; ++r)
          hv[r] = (_Float16)fmaxf(a1[mt][nt][r] + bb[r], 0.f);
        *(half4*)(h1b + (nt * 16 + l16) * H1STR + colbase) = hv;
      }
    }

    __syncthreads();   // h1[e&1] ready — the ONLY barrier per expert

    // ================= L2: h2 = h1 @ W2, wave owns h2cols [w*32,w*32+32) ===
    float4_t h2[4][2];
    #pragma unroll
    for (int mt = 0; mt < 4; ++mt)
      #pragma unroll
      for (int nt = 0; nt < 2; ++nt)
        h2[mt][nt] = (float4_t){0.f, 0.f, 0.f, 0.f};

    half8 w2c[2], w2n[2], hac[4], han[4];
    #pragma unroll
    for (int nt = 0; nt < 2; ++nt)
      w2c[nt] = *(const half8*)(w2e + (size_t)(nt * 16 + 0) * 512);
    #pragma unroll
    for (int mt = 0; mt < 4; ++mt)
      hac[mt] = *(const half8*)(h1b + (mt * 16 + l16) * H1STR + 0 * 32 + q * 8);

    #pragma unroll
    for (int kt = 0; kt < 16; ++kt) {
      if (kt < 15) {
        #pragma unroll
        for (int nt = 0; nt < 2; ++nt)
          w2n[nt] = *(const half8*)(w2e + (size_t)(nt * 16 + kt + 1) * 512);
        #pragma unroll
        for (int mt = 0; mt < 4; ++mt)
          han[mt] = *(const half8*)(h1b + (mt * 16 + l16) * H1STR + (kt + 1) * 32 + q * 8);
      }
      #pragma unroll
      for (int mt = 0; mt < 4; ++mt)
        #pragma unroll
        for (int nt = 0; nt < 2; ++nt)
          h2[mt][nt] = __builtin_amdgcn_mfma_f32_16x16x32_f16(
              hac[mt], w2c[nt], h2[mt][nt], 0, 0, 0);
      #pragma unroll
      for (int nt = 0; nt < 2; ++nt) w2c[nt] = w2n[nt];
      #pragma unroll
      for (int mt = 0; mt < 4; ++mt) hac[mt] = han[mt];
    }

    // ---- register-only epilogue: relu(h2+b2) . w3h, gate, accumulate ------
    float b2v[2], w3v[2];
    #pragma unroll
    for (int nt = 0; nt < 2; ++nt) {
      int n = w * 32 + nt * 16 + l16;
      b2v[nt] = b2[e * H2D + n];
      w3v[nt] = w3h[e * H2D + n];
    }
    float s[4][4];
    #pragma unroll
    for (int mt = 0; mt < 4; ++mt)
      #pragma unroll
      for (int r = 0; r < 4; ++r) s[mt][r] = 0.f;
    #pragma unroll
    for (int mt = 0; mt < 4; ++mt)
      #pragma unroll
      for (int nt = 0; nt < 2; ++nt)
        #pragma unroll
        for (int r = 0; r < 4; ++r)
          s[mt][r] += fmaxf(h2[mt][nt][r] + b2v[nt], 0.f) * w3v[nt];

    float ge = g_lds[e * 68 + tok_lane];
    #pragma unroll
    for (int i = 0; i < 16; ++i) {
      float v = s[i >> 2][i & 3];
      v += __shfl_xor(v, 1);
      v += __shfl_xor(v, 2);
      v += __shfl_xor(v, 4);
      v += __shfl_xor(v, 8);
      if (l16 == i) yacc += ge * v;
    }
    // NO barrier: next L1 writes the other h1 buffer; reads of this buffer
    // by any wave finish before that wave's next barrier.
  }

  // ---- final cross-wave reduction + gate.c3 + head bias ----
  fin[w * 64 + tok_lane] = yacc;
  __syncthreads();
  if (tid < 64) {
    float sum = 0.f;
    #pragma unroll
    for (int k = 0; k < 8; ++k) sum += fin[k * 64 + tid];
    float gc = 0.f;
    #pragma unroll
    for (int e = 0; e < NE; ++e) gc += g_lds[e * 68 + tid] * c3[e];
    out[m0 + tid] = sum + gc + head_b[0];
  }
}

// ---------------------------------------------------------------------------
extern "C" void kernel_launch(void* const* d_in, const int* in_sizes, int n_in,
                              void* d_out, int out_size, void* d_ws, size_t ws_size,
                              hipStream_t stream) {
  const float* x      = (const float*)d_in[0];
  const float* gate_w = (const float*)d_in[1];
  const float* gate_b = (const float*)d_in[2];
  const float* W1     = (const float*)d_in[3];
  const float* b1     = (const float*)d_in[4];
  const float* W2     = (const float*)d_in[5];
  const float* b2     = (const float*)d_in[6];
  const float* W3     = (const float*)d_in[7];
  const float* b3     = (const float*)d_in[8];
  const float* head_w = (const float*)d_in[9];
  const float* head_b = (const float*)d_in[10];
  float* out = (float*)d_out;

  // workspace layout (16B-aligned)
  char* ws = (char*)d_ws;
  _Float16* w1p = (_Float16*)(ws);                 // 4,194,304 B
  _Float16* w2p = (_Float16*)(ws + 4194304);       // 4,194,304 B
  _Float16* gwp = (_Float16*)(ws + 8388608);       // 8,192 B
  float*    w3h = (float*)(ws + 8396800);          // 16,384 B
  float*    c3  = (float*)(ws + 8413184);          // 64 B

  hipLaunchKernelGGL(pack_w1, dim3(1024), dim3(256), 0, stream, W1, w1p);
  hipLaunchKernelGGL(pack_w2, dim3(1024), dim3(256), 0, stream, W2, w2p);
  hipLaunchKernelGGL(pack_gate, dim3(1), dim3(512), 0, stream, gate_w, gwp);
  hipLaunchKernelGGL(w3h_kernel, dim3(17), dim3(256), 0, stream,
                     W3, b3, head_w, w3h, c3);
  hipLaunchKernelGGL(moe_main, dim3(B_TOK / 64), dim3(512), 0, stream,
                     x, b1, b2, w1p, w2p, gwp, gate_b, w3h, c3, head_b, out);
}